// Round 1
// baseline (7263.608 us; speedup 1.0000x reference)
//
#include <hip/hip_runtime.h>

#define B_     128
#define T_     160
#define ENC_   1024
#define EMB_   512
#define PRED_  640
#define JOINT_ 512
#define V_     1024
#define NS_    48
#define LOWV   (-10000.0f)

__device__ __forceinline__ float sigf(float x){ return 1.0f/(1.0f+expf(-x)); }
// order-preserving float -> uint key
__device__ __forceinline__ unsigned fkey(float f){
    unsigned u = __float_as_uint(f);
    return (u & 0x80000000u) ? ~u : (u | 0x80000000u);
}
__device__ __forceinline__ float funkey(unsigned k){
    unsigned u = (k & 0x80000000u) ? (k ^ 0x80000000u) : ~k;
    return __uint_as_float(u);
}

// ---------- init: gate-interleaved transposes of Wh, Wi; bsum = bi+bh ----------
__global__ __launch_bounds__(256) void k_t0(const float* __restrict__ Wh, const float* __restrict__ Wi,
        const float* __restrict__ bi, const float* __restrict__ bh,
        float4* __restrict__ Whx, float4* __restrict__ Wix, float4* __restrict__ bsum){
    int idx = blockIdx.x*256 + threadIdx.x;
    const int NWH = PRED_*PRED_;
    const int NWI = EMB_*PRED_;
    if (idx < NWH){
        int k = idx / PRED_, j = idx - k*PRED_;
        const float* row = Wh + (size_t)k*4*PRED_;
        Whx[idx] = make_float4(row[j], row[PRED_+j], row[2*PRED_+j], row[3*PRED_+j]);
    } else if (idx < NWH+NWI){
        int i2 = idx - NWH;
        int k = i2 / PRED_, j = i2 - k*PRED_;
        const float* row = Wi + (size_t)k*4*PRED_;
        Wix[i2] = make_float4(row[j], row[PRED_+j], row[2*PRED_+j], row[3*PRED_+j]);
    } else if (idx < NWH+NWI+PRED_){
        int j = idx - NWH - NWI;
        bsum[j] = make_float4(bi[j]+bh[j], bi[PRED_+j]+bh[PRED_+j],
                              bi[2*PRED_+j]+bh[2*PRED_+j], bi[3*PRED_+j]+bh[3*PRED_+j]);
    }
}

// ---------- init: EWiT[v][j'] (float4 gates) = (E @ Wi) transposed ----------
__global__ __launch_bounds__(256) void k_ewi(const float* __restrict__ E, const float4* __restrict__ Wix,
        float4* __restrict__ EWiT){
    int tid = threadIdx.x, lane = tid & 63, vg = tid >> 6;
    int jb = blockIdx.x % 10, vb = blockIdx.x / 10;
    int j  = jb*64 + lane;
    int v0 = vb*16 + vg*4;
    float4 a0 = make_float4(0,0,0,0), a1 = a0, a2 = a0, a3 = a0;
    const float* e0 = E + (size_t)(v0+0)*EMB_;
    const float* e1 = E + (size_t)(v0+1)*EMB_;
    const float* e2 = E + (size_t)(v0+2)*EMB_;
    const float* e3 = E + (size_t)(v0+3)*EMB_;
    #pragma unroll 2
    for (int k=0;k<EMB_;++k){
        float4 w4 = Wix[k*PRED_ + j];
        float x0=e0[k], x1=e1[k], x2=e2[k], x3=e3[k];
        a0.x+=x0*w4.x; a0.y+=x0*w4.y; a0.z+=x0*w4.z; a0.w+=x0*w4.w;
        a1.x+=x1*w4.x; a1.y+=x1*w4.y; a1.z+=x1*w4.z; a1.w+=x1*w4.w;
        a2.x+=x2*w4.x; a2.y+=x2*w4.y; a2.z+=x2*w4.z; a2.w+=x2*w4.w;
        a3.x+=x3*w4.x; a3.y+=x3*w4.y; a3.z+=x3*w4.z; a3.w+=x3*w4.w;
    }
    EWiT[(size_t)(v0+0)*PRED_ + j] = a0;
    EWiT[(size_t)(v0+1)*PRED_ + j] = a1;
    EWiT[(size_t)(v0+2)*PRED_ + j] = a2;
    EWiT[(size_t)(v0+3)*PRED_ + j] = a3;
}

// ---------- init: encP(t=0), h0/c0 state, zero atomics/scalars ----------
__global__ __launch_bounds__(256) void k_is(const float* __restrict__ encoder, const float* __restrict__ Wenc,
        const float4* __restrict__ EWiT, const float4* __restrict__ bsum,
        float* __restrict__ encP, float* __restrict__ hbuf, float* __restrict__ cbuf,
        int* __restrict__ actA, int* __restrict__ encT, int* __restrict__ nEm, float* __restrict__ scoresA,
        unsigned long long* __restrict__ packed, float* __restrict__ sumexp){
    int bid = blockIdx.x, tid = threadIdx.x, lane = tid & 63;
    if (bid < 128){
        int jb = bid & 3, rb = bid >> 2;
        int r  = rb*4 + (tid >> 6);
        int c0 = jb*128 + lane*2;
        const float* e = encoder + (size_t)r*T_*ENC_;   // frame 0
        float ax=0.f, ay=0.f;
        #pragma unroll 4
        for (int k=0;k<ENC_;++k){
            float ek = e[k];
            float2 wv = *(const float2*)(Wenc + (size_t)k*JOINT_ + c0);
            ax += ek*wv.x; ay += ek*wv.y;
        }
        encP[r*JOINT_ + c0]   = ax;
        encP[r*JOINT_ + c0+1] = ay;
    } else if (bid < 131){
        int j = (bid-128)*256 + tid;
        if (j < PRED_){
            float4 g  = EWiT[j];      // v = OB = 0
            float4 bs = bsum[j];
            float gi=g.x+bs.x, gf=g.y+bs.y, gg=g.z+bs.z, go=g.w+bs.w;
            (void)gf; // f * c0 with c0 = 0
            float c0v = sigf(gi)*tanhf(gg);
            float h0v = tanhf(c0v)*sigf(go);
            for (int r=0;r<B_;++r){ hbuf[r*PRED_+j] = h0v; cbuf[r*PRED_+j] = c0v; }
        }
    } else if (bid < 155){
        int idx = (bid-131)*256 + tid;   // exactly 6144
        packed[idx] = 0ULL;
        sumexp[idx] = 0.0f;
    } else {
        if (tid < B_){
            actA[tid] = 1; encT[tid] = 0; nEm[tid] = 0; scoresA[tid] = 0.0f;
        }
    }
}

// ---------- per step: joint = tanh(encP + h @ W_pred + bj) ----------
__global__ __launch_bounds__(256) void kA(int p, const float* __restrict__ hbuf, const float* __restrict__ encP,
        const float* __restrict__ Wpred, const float* __restrict__ bj, const int* __restrict__ actA,
        float* __restrict__ joint){
    int bid = blockIdx.x, tid = threadIdx.x, lane = tid & 63;
    int jb = bid & 3, rb = bid >> 2;
    int r  = rb*4 + (tid >> 6);
    if (!actA[p*B_ + r]) return;
    int c0 = jb*128 + lane*2;
    const float* hr = hbuf + (size_t)p*B_*PRED_ + (size_t)r*PRED_;
    float ax=0.f, ay=0.f;
    #pragma unroll 4
    for (int k=0;k<PRED_;++k){
        float hk = hr[k];
        float2 w2 = *(const float2*)(Wpred + (size_t)k*JOINT_ + c0);
        ax += hk*w2.x; ay += hk*w2.y;
    }
    joint[r*JOINT_+c0]   = tanhf(ax + encP[r*JOINT_+c0]   + bj[c0]);
    joint[r*JOINT_+c0+1] = tanhf(ay + encP[r*JOINT_+c0+1] + bj[c0+1]);
}

// ---------- per step: logits + fused argmax(ext) + sum(exp(logits)) ----------
__global__ __launch_bounds__(256) void kB(int s, int p, const float* __restrict__ joint,
        const float* __restrict__ Wout, const int* __restrict__ actA, const int* __restrict__ nEm,
        unsigned long long* __restrict__ packed, float* __restrict__ sumexp){
    int bid = blockIdx.x, tid = threadIdx.x, lane = tid & 63;
    int jb = bid & 3, rb = bid >> 2;
    int r  = rb*4 + (tid >> 6);
    if (!actA[p*B_ + r]) return;
    int c0 = jb*256 + lane*4;
    bool force = (nEm[p*B_ + r] >= 2);
    const float* jr = joint + (size_t)r*JOINT_;
    float4 acc = make_float4(0,0,0,0);
    #pragma unroll 4
    for (int k=0;k<JOINT_;++k){
        float jk = jr[k];
        float4 w4 = *(const float4*)(Wout + (size_t)k*V_ + c0);
        acc.x += jk*w4.x; acc.y += jk*w4.y; acc.z += jk*w4.z; acc.w += jk*w4.w;
    }
    float v[4] = {acc.x, acc.y, acc.z, acc.w};
    float es = expf(v[0]) + expf(v[1]) + expf(v[2]) + expf(v[3]);
    unsigned long long best = 0ULL;
    #pragma unroll
    for (int i=0;i<4;++i){
        int c = c0 + i;
        int idx  = (c == 0) ? V_ : c;                       // col 0 -> appended blank col
        float va = (c == 0) ? v[i] : (force ? LOWV : v[i]); // force kills non-blank cols
        unsigned long long pk = ((unsigned long long)fkey(va) << 32) | (unsigned)(2047 - idx);
        if (pk > best) best = pk;
    }
    #pragma unroll
    for (int off=32; off>0; off>>=1){
        unsigned lo = __shfl_xor((unsigned)best, off, 64);
        unsigned hi = __shfl_xor((unsigned)(best >> 32), off, 64);
        unsigned long long o = ((unsigned long long)hi << 32) | lo;
        if (o > best) best = o;
        es += __shfl_xor(es, off, 64);
    }
    if (lane == 0){
        atomicMax(packed + (size_t)s*B_ + r, best);
        atomicAdd(sumexp + (size_t)s*B_ + r, es);
    }
}

// ---------- per step: LSTM (part1) | encP advance (part2) | scalar state + tokens (part3) ----------
__global__ __launch_bounds__(256) void kD(int s, int p,
        const unsigned long long* __restrict__ packed, const float* __restrict__ sumexp,
        const float4* __restrict__ EWiT, const float4* __restrict__ Whx, const float4* __restrict__ bsum,
        float* __restrict__ hbuf, float* __restrict__ cbuf,
        const float* __restrict__ encoder, const float* __restrict__ Wenc, float* __restrict__ encP,
        const int* __restrict__ lengths,
        int* __restrict__ actA, int* __restrict__ encT, int* __restrict__ nEm, float* __restrict__ scoresA,
        float* __restrict__ out){
    int w = 1 - p;
    int bid = blockIdx.x, tid = threadIdx.x, lane = tid & 63;
    if (bid < 320){
        // LSTM gates: thread = (row r, pred-col j, 4 gates)
        int jb = bid % 10, rb = bid / 10;
        int r = rb*4 + (tid >> 6);
        int j = jb*64 + lane;
        const float* hp = hbuf + (size_t)p*B_*PRED_;
        float*       hw = hbuf + (size_t)w*B_*PRED_;
        const float* cp = cbuf + (size_t)p*B_*PRED_;
        float*       cw = cbuf + (size_t)w*B_*PRED_;
        unsigned long long pk = packed[(size_t)s*B_ + r];
        int tok = 2047 - (int)(unsigned)(pk & 0xffffffffu);
        int act = actA[p*B_ + r];
        bool upd = act && (tok != V_);
        if (!upd){
            hw[r*PRED_ + j] = hp[r*PRED_ + j];
            cw[r*PRED_ + j] = cp[r*PRED_ + j];
            return;
        }
        float4 acc = make_float4(0,0,0,0);
        const float* hr = hp + (size_t)r*PRED_;
        #pragma unroll 4
        for (int k=0;k<PRED_;++k){
            float hk = hr[k];
            float4 w4 = Whx[k*PRED_ + j];
            acc.x += hk*w4.x; acc.y += hk*w4.y; acc.z += hk*w4.z; acc.w += hk*w4.w;
        }
        float4 ew = EWiT[(size_t)tok*PRED_ + j];
        float4 bs = bsum[j];
        float gi = acc.x + ew.x + bs.x;
        float gf = acc.y + ew.y + bs.y;
        float gg = acc.z + ew.z + bs.z;
        float go = acc.w + ew.w + bs.w;
        float cold = cp[r*PRED_ + j];
        float c2 = sigf(gf)*cold + sigf(gi)*tanhf(gg);
        float h2 = tanhf(c2)*sigf(go);
        hw[r*PRED_ + j] = h2;
        cw[r*PRED_ + j] = c2;
    } else if (bid < 448){
        // encoder projection for rows that consumed a blank
        int b2 = bid - 320;
        int jb = b2 & 3, rb = b2 >> 2;
        int r  = rb*4 + (tid >> 6);
        if (!actA[p*B_ + r]) return;
        unsigned long long pk = packed[(size_t)s*B_ + r];
        int tok = 2047 - (int)(unsigned)(pk & 0xffffffffu);
        if (tok != V_) return;
        int c0 = jb*128 + lane*2;
        int t = encT[p*B_ + r] + 1;
        if (t > T_-1) t = T_-1;
        const float* e = encoder + ((size_t)r*T_ + t)*ENC_;
        float ax=0.f, ay=0.f;
        #pragma unroll 4
        for (int k=0;k<ENC_;++k){
            float ek = e[k];
            float2 wv = *(const float2*)(Wenc + (size_t)k*JOINT_ + c0);
            ax += ek*wv.x; ay += ek*wv.y;
        }
        encP[r*JOINT_ + c0]   = ax;
        encP[r*JOINT_ + c0+1] = ay;
    } else if (bid == 448){
        int r = tid;
        if (r < B_){
            int act = actA[p*B_ + r];
            int et  = encT[p*B_ + r];
            int ne  = nEm[p*B_ + r];
            float sc = scoresA[p*B_ + r];
            int len = lengths[r];
            int tok_out = V_, act_n = 0;
            if (act){
                unsigned long long pk = packed[(size_t)s*B_ + r];
                int tok = 2047 - (int)(unsigned)(pk & 0xffffffffu);
                float chosen = funkey((unsigned)(pk >> 32));
                float lse = logf(sumexp[(size_t)s*B_ + r]);
                float tlp = chosen - lse;
                int isb = (tok == V_);
                sc += tlp;
                et += isb ? 1 : 0;
                ne  = isb ? 0 : ne + 1;
                act_n = (et < len) ? 1 : 0;
                tok_out = (act_n || isb) ? tok : V_;
            }
            actA[w*B_ + r] = act_n;
            encT[w*B_ + r] = et;
            nEm[w*B_ + r]  = ne;
            scoresA[w*B_ + r] = sc;
            out[(size_t)r*NS_ + s] = (float)tok_out;
            if (s == NS_-1) out[(size_t)B_*NS_ + r] = sc;
        }
    }
}

extern "C" void kernel_launch(void* const* d_in, const int* in_sizes, int n_in,
                              void* d_out, int out_size, void* d_ws, size_t ws_size,
                              hipStream_t stream) {
    const float* enc   = (const float*)d_in[0];
    const int*   lens  = (const int*)  d_in[1];
    // d_in[2] = nbest (unused, == 1)
    const float* E     = (const float*)d_in[3];
    const float* Wi    = (const float*)d_in[4];
    const float* Wh    = (const float*)d_in[5];
    const float* bi    = (const float*)d_in[6];
    const float* bh    = (const float*)d_in[7];
    const float* Wenc  = (const float*)d_in[8];
    const float* Wpred = (const float*)d_in[9];
    const float* bj    = (const float*)d_in[10];
    const float* Wout  = (const float*)d_in[11];
    float* out = (float*)d_out;

    char* base = (char*)d_ws;
    size_t off = 0;
    auto carve = [&](size_t bytes) -> void* {
        void* pp = base + off;
        off += (bytes + 255) & ~(size_t)255;
        return pp;
    };
    float4* EWiT = (float4*)carve((size_t)V_*PRED_*16);      // 10 MB
    float4* Whx  = (float4*)carve((size_t)PRED_*PRED_*16);   // 6.25 MB
    float4* Wix  = (float4*)carve((size_t)EMB_*PRED_*16);    // 5 MB
    float4* bsum = (float4*)carve((size_t)PRED_*16);
    float*  encP = (float*)carve((size_t)B_*JOINT_*4);
    float*  joint= (float*)carve((size_t)B_*JOINT_*4);
    float*  hbuf = (float*)carve((size_t)2*B_*PRED_*4);
    float*  cbuf = (float*)carve((size_t)2*B_*PRED_*4);
    float*  scoresA = (float*)carve(2*B_*4);
    int*    encT = (int*)carve(2*B_*4);
    int*    nEm  = (int*)carve(2*B_*4);
    int*    actA = (int*)carve(2*B_*4);
    unsigned long long* packed = (unsigned long long*)carve((size_t)NS_*B_*8);
    float*  sumexp = (float*)carve((size_t)NS_*B_*4);
    (void)ws_size; (void)in_sizes; (void)n_in; (void)out_size;

    k_t0 <<<2883, 256, 0, stream>>>(Wh, Wi, bi, bh, Whx, Wix, bsum);
    k_ewi<<<640,  256, 0, stream>>>(E, Wix, EWiT);
    k_is <<<156,  256, 0, stream>>>(enc, Wenc, EWiT, bsum, encP, hbuf, cbuf,
                                    actA, encT, nEm, scoresA, packed, sumexp);
    for (int s = 0; s < NS_; ++s){
        int p = s & 1;
        kA<<<128, 256, 0, stream>>>(p, hbuf, encP, Wpred, bj, actA, joint);
        kB<<<128, 256, 0, stream>>>(s, p, joint, Wout, actA, nEm, packed, sumexp);
        kD<<<449, 256, 0, stream>>>(s, p, packed, sumexp, EWiT, Whx, bsum, hbuf, cbuf,
                                    enc, Wenc, encP, lens, actA, encT, nEm, scoresA, out);
    }
}

// Round 2
// 5539.475 us; speedup vs baseline: 1.3112x; 1.3112x over previous
//
#include <hip/hip_runtime.h>

#define B_     128
#define T_     160
#define ENC_   1024
#define EMB_   512
#define PRED_  640
#define JOINT_ 512
#define V_     1024
#define NS_    48
#define LOWV   (-10000.0f)

__device__ __forceinline__ float sigf(float x){ return 1.0f/(1.0f+expf(-x)); }
__device__ __forceinline__ unsigned fkey(float f){
    unsigned u = __float_as_uint(f);
    return (u & 0x80000000u) ? ~u : (u | 0x80000000u);
}
__device__ __forceinline__ float funkey(unsigned k){
    unsigned u = (k & 0x80000000u) ? (k ^ 0x80000000u) : ~k;
    return __uint_as_float(u);
}

// ---------- init: gate-interleaved transpose of Wh ----------
__global__ __launch_bounds__(256) void k_t0(const float* __restrict__ Wh, float4* __restrict__ Whx){
    int idx = blockIdx.x*256 + threadIdx.x;      // 640*640 elements, 1600 blocks
    int k = idx / PRED_, j = idx - k*PRED_;
    const float* row = Wh + (size_t)k*4*PRED_;
    Whx[idx] = make_float4(row[j], row[PRED_+j], row[2*PRED_+j], row[3*PRED_+j]);
}

// ---------- init: EWi[v][4*PRED] = E @ Wi + (bi+bh), plain gate-blocked layout ----------
__global__ __launch_bounds__(256) void k_ewi(const float* __restrict__ E, const float* __restrict__ Wi,
        const float* __restrict__ bi, const float* __restrict__ bh, float* __restrict__ EWi){
    int tid = threadIdx.x, lane = tid & 63, vg = tid >> 6;
    int jb = blockIdx.x % 10, vb = blockIdx.x / 10;   // 320 blocks
    int j  = jb*64 + lane;
    int v0 = vb*32 + vg*8;
    float acc[8][4];
    #pragma unroll
    for (int i=0;i<8;++i)
        #pragma unroll
        for (int g=0;g<4;++g) acc[i][g] = 0.f;
    const float* e = E + (size_t)v0*EMB_;
    for (int k0=0; k0<EMB_; k0+=4){
        float ev[8][4];
        #pragma unroll
        for (int i=0;i<8;++i) *(float4*)ev[i] = *(const float4*)(e + (size_t)i*EMB_ + k0);
        #pragma unroll
        for (int kk=0;kk<4;++kk){
            const float* wrow = Wi + (size_t)(k0+kk)*4*PRED_ + j;
            #pragma unroll
            for (int g=0;g<4;++g){
                float wg = wrow[g*PRED_];
                #pragma unroll
                for (int i=0;i<8;++i) acc[i][g] += ev[i][kk]*wg;
            }
        }
    }
    #pragma unroll
    for (int g=0;g<4;++g){
        float bs = bi[g*PRED_+j] + bh[g*PRED_+j];
        #pragma unroll
        for (int i=0;i<8;++i) EWi[(size_t)(v0+i)*4*PRED_ + g*PRED_ + j] = acc[i][g] + bs;
    }
}

// ---------- init: encP(frame 0), h0/c0, zero atomics, scalar state ----------
__global__ __launch_bounds__(256) void k_is(const float* __restrict__ enc, const float* __restrict__ Wenc,
        const float* __restrict__ EWi,
        float* __restrict__ encP, float* __restrict__ hbuf, float* __restrict__ cbuf,
        int* __restrict__ actA, int* __restrict__ encT, int* __restrict__ nEm, float* __restrict__ scoresA,
        unsigned long long* __restrict__ packed, float* __restrict__ sumexp){
    int bid = blockIdx.x, tid = threadIdx.x, lane = tid & 63;
    if (bid < 128){
        int jb = bid & 3, rb = bid >> 2;
        int r  = rb*4 + (tid >> 6);
        int c0 = jb*128 + lane*2;
        const float* e = enc + (size_t)r*T_*ENC_;   // frame 0
        float ax=0.f, ay=0.f;
        #pragma unroll 8
        for (int k=0;k<ENC_;++k){
            float ek = e[k];
            float2 w2 = *(const float2*)(Wenc + (size_t)k*JOINT_ + c0);
            ax += ek*w2.x; ay += ek*w2.y;
        }
        encP[r*JOINT_ + c0]   = ax;
        encP[r*JOINT_ + c0+1] = ay;
    } else if (bid < 131){
        int j = (bid-128)*256 + tid;
        if (j < PRED_){
            float gi = EWi[j], gg = EWi[2*PRED_+j], go = EWi[3*PRED_+j];  // bsum folded in
            float c0v = sigf(gi)*tanhf(gg);
            float h0v = tanhf(c0v)*sigf(go);
            for (int r=0;r<B_;++r){ hbuf[r*PRED_+j] = h0v; cbuf[r*PRED_+j] = c0v; }
        }
    } else if (bid < 155){
        int idx = (bid-131)*256 + tid;   // 6144
        packed[idx] = 0ULL;
        sumexp[idx] = 0.0f;
    } else {
        if (tid < B_){ actA[tid]=1; encT[tid]=0; nEm[tid]=0; scoresA[tid]=0.0f; }
    }
}

// ---------- per step: joint = tanh(encP + h @ W_pred + bj) ----------
__global__ __launch_bounds__(256) void kA(int p, const float* __restrict__ hbuf, const float* __restrict__ encP,
        const float* __restrict__ Wpred, const float* __restrict__ bj, const int* __restrict__ actA,
        float* __restrict__ joint){
    int tid = threadIdx.x, lane = tid & 63;
    int jb = blockIdx.x & 3, rb = blockIdx.x >> 2;
    int r  = rb*4 + (tid >> 6);
    if (!actA[p*B_ + r]) return;
    int c0 = jb*128 + lane*2;
    const float* hr = hbuf + (size_t)p*B_*PRED_ + (size_t)r*PRED_;
    float ax=0.f, ay=0.f;
    #pragma unroll 16
    for (int k=0;k<PRED_;++k){
        float hk = hr[k];
        float2 w2 = *(const float2*)(Wpred + (size_t)k*JOINT_ + c0);
        ax += hk*w2.x; ay += hk*w2.y;
    }
    joint[r*JOINT_+c0]   = tanhf(ax + encP[r*JOINT_+c0]   + bj[c0]);
    joint[r*JOINT_+c0+1] = tanhf(ay + encP[r*JOINT_+c0+1] + bj[c0+1]);
}

// ---------- per step: logits + fused argmax(ext) + sum(exp(logits)) ----------
__global__ __launch_bounds__(256) void kB(int s, int p, const float* __restrict__ joint,
        const float* __restrict__ Wout, const int* __restrict__ actA, const int* __restrict__ nEm,
        unsigned long long* __restrict__ packed, float* __restrict__ sumexp){
    int tid = threadIdx.x, lane = tid & 63;
    int jb = blockIdx.x & 3, rb = blockIdx.x >> 2;
    int r  = rb*4 + (tid >> 6);
    if (!actA[p*B_ + r]) return;
    int c0 = jb*256 + lane*4;
    bool force = (nEm[p*B_ + r] >= 2);
    const float* jr = joint + (size_t)r*JOINT_;
    float4 acc = make_float4(0,0,0,0);
    #pragma unroll 8
    for (int k=0;k<JOINT_;++k){
        float jk = jr[k];
        float4 w4 = *(const float4*)(Wout + (size_t)k*V_ + c0);
        acc.x += jk*w4.x; acc.y += jk*w4.y; acc.z += jk*w4.z; acc.w += jk*w4.w;
    }
    float v[4] = {acc.x, acc.y, acc.z, acc.w};
    float es = expf(v[0]) + expf(v[1]) + expf(v[2]) + expf(v[3]);
    unsigned long long best = 0ULL;
    #pragma unroll
    for (int i=0;i<4;++i){
        int c = c0 + i;
        int idx  = (c == 0) ? V_ : c;                       // col 0 -> appended blank col
        float va = (c == 0) ? v[i] : (force ? LOWV : v[i]); // force kills non-blank cols
        unsigned long long pk = ((unsigned long long)fkey(va) << 32) | (unsigned)(2047 - idx);
        if (pk > best) best = pk;
    }
    #pragma unroll
    for (int off=32; off>0; off>>=1){
        unsigned lo = __shfl_xor((unsigned)best, off, 64);
        unsigned hi = __shfl_xor((unsigned)(best >> 32), off, 64);
        unsigned long long o = ((unsigned long long)hi << 32) | lo;
        if (o > best) best = o;
        es += __shfl_xor(es, off, 64);
    }
    if (lane == 0){
        atomicMax(packed + (size_t)s*B_ + r, best);
        atomicAdd(sumexp + (size_t)s*B_ + r, es);
    }
}

// ---------- per step: LSTM | lazy encP | scalar state + tokens (512 threads) ----------
__global__ __launch_bounds__(512) void kD(int s, int p,
        const unsigned long long* __restrict__ packed, const float* __restrict__ sumexp,
        const float* __restrict__ EWi, const float4* __restrict__ Whx,
        float* __restrict__ hbuf, float* __restrict__ cbuf,
        const float* __restrict__ enc, const float* __restrict__ Wenc, float* __restrict__ encP,
        const int* __restrict__ lengths,
        int* __restrict__ actA, int* __restrict__ encT, int* __restrict__ nEm, float* __restrict__ scoresA,
        float* __restrict__ out){
    int w = 1 - p;
    int bid = blockIdx.x, tid = threadIdx.x, lane = tid & 63, wv = tid >> 6;
    if (bid < 160){
        // LSTM: wave = row, 8 rows/block, 64-col gate-packed slice
        int jb = bid % 10, rb = bid / 10;
        int r = rb*8 + wv;
        int j = jb*64 + lane;
        const float* hp = hbuf + (size_t)p*B_*PRED_;
        float*       hw = hbuf + (size_t)w*B_*PRED_;
        unsigned long long pk = packed[(size_t)s*B_ + r];
        int tok = 2047 - (int)(unsigned)(pk & 0xffffffffu);
        int act = actA[p*B_ + r];
        if (!(act && tok != V_)){
            hw[r*PRED_ + j] = hp[r*PRED_ + j];   // c unchanged (single-buffered)
            return;
        }
        float ax=0.f, ay=0.f, az=0.f, aw=0.f;
        const float* hr = hp + (size_t)r*PRED_;
        #pragma unroll 8
        for (int k=0;k<PRED_;++k){
            float hk = hr[k];
            float4 w4 = Whx[k*PRED_ + j];
            ax += hk*w4.x; ay += hk*w4.y; az += hk*w4.z; aw += hk*w4.w;
        }
        const float* ew = EWi + (size_t)tok*4*PRED_ + j;
        float gi = ax + ew[0];
        float gf = ay + ew[PRED_];
        float gg = az + ew[2*PRED_];
        float go = aw + ew[3*PRED_];
        float cold = cbuf[r*PRED_ + j];
        float c2 = sigf(gf)*cold + sigf(gi)*tanhf(gg);
        float h2 = tanhf(c2)*sigf(go);
        hw[r*PRED_ + j] = h2;
        cbuf[r*PRED_ + j] = c2;
    } else if (bid < 192){
        // lazy encoder projection for rows that consumed a blank
        int b2 = bid - 160;
        int rb = b2 >> 1, jb = b2 & 1;
        int r  = rb*8 + wv;
        if (!actA[p*B_ + r]) return;
        unsigned long long pk = packed[(size_t)s*B_ + r];
        int tok = 2047 - (int)(unsigned)(pk & 0xffffffffu);
        if (tok != V_) return;
        int c0 = jb*256 + lane*4;
        int t = encT[p*B_ + r] + 1;
        if (t > T_-1) t = T_-1;
        const float* e = enc + ((size_t)r*T_ + t)*ENC_;
        float a0=0.f,a1=0.f,a2=0.f,a3=0.f;
        #pragma unroll 8
        for (int k=0;k<ENC_;++k){
            float ek = e[k];
            float4 w4 = *(const float4*)(Wenc + (size_t)k*JOINT_ + c0);
            a0 += ek*w4.x; a1 += ek*w4.y; a2 += ek*w4.z; a3 += ek*w4.w;
        }
        *(float4*)(encP + r*JOINT_ + c0) = make_float4(a0,a1,a2,a3);
    } else {
        if (tid < B_){
            int r = tid;
            int act = actA[p*B_ + r];
            int et  = encT[p*B_ + r];
            int ne  = nEm[p*B_ + r];
            float sc = scoresA[p*B_ + r];
            int len = lengths[r];
            int tok_out = V_, act_n = 0;
            if (act){
                unsigned long long pk = packed[(size_t)s*B_ + r];
                int tok = 2047 - (int)(unsigned)(pk & 0xffffffffu);
                float chosen = funkey((unsigned)(pk >> 32));
                float lse = logf(sumexp[(size_t)s*B_ + r]);
                float tlp = chosen - lse;
                int isb = (tok == V_);
                sc += tlp;
                et += isb ? 1 : 0;
                ne  = isb ? 0 : ne + 1;
                act_n = (et < len) ? 1 : 0;
                tok_out = (act_n || isb) ? tok : V_;
            }
            actA[w*B_ + r] = act_n;
            encT[w*B_ + r] = et;
            nEm[w*B_ + r]  = ne;
            scoresA[w*B_ + r] = sc;
            out[(size_t)r*NS_ + s] = (float)tok_out;
            if (s == NS_-1) out[(size_t)B_*NS_ + r] = sc;
        }
    }
}

extern "C" void kernel_launch(void* const* d_in, const int* in_sizes, int n_in,
                              void* d_out, int out_size, void* d_ws, size_t ws_size,
                              hipStream_t stream) {
    const float* enc   = (const float*)d_in[0];
    const int*   lens  = (const int*)  d_in[1];
    const float* E     = (const float*)d_in[3];
    const float* Wi    = (const float*)d_in[4];
    const float* Wh    = (const float*)d_in[5];
    const float* bi    = (const float*)d_in[6];
    const float* bh    = (const float*)d_in[7];
    const float* Wenc  = (const float*)d_in[8];
    const float* Wpred = (const float*)d_in[9];
    const float* bj    = (const float*)d_in[10];
    const float* Wout  = (const float*)d_in[11];
    float* out = (float*)d_out;

    char* base = (char*)d_ws;
    size_t off = 0;
    auto carve = [&](size_t bytes) -> void* {
        void* pp = base + off;
        off += (bytes + 255) & ~(size_t)255;
        return pp;
    };
    float*  EWi  = (float*)carve((size_t)V_*4*PRED_*4);      // 10.5 MB
    float4* Whx  = (float4*)carve((size_t)PRED_*PRED_*16);   // 6.55 MB
    float*  encP = (float*)carve((size_t)B_*JOINT_*4);
    float*  joint= (float*)carve((size_t)B_*JOINT_*4);
    float*  hbuf = (float*)carve((size_t)2*B_*PRED_*4);
    float*  cbuf = (float*)carve((size_t)B_*PRED_*4);
    float*  scoresA = (float*)carve(2*B_*4);
    int*    encT = (int*)carve(2*B_*4);
    int*    nEm  = (int*)carve(2*B_*4);
    int*    actA = (int*)carve(2*B_*4);
    unsigned long long* packed = (unsigned long long*)carve((size_t)NS_*B_*8);
    float*  sumexp = (float*)carve((size_t)NS_*B_*4);
    (void)ws_size; (void)in_sizes; (void)n_in; (void)out_size;

    k_t0 <<<1600, 256, 0, stream>>>(Wh, Whx);
    k_ewi<<<320,  256, 0, stream>>>(E, Wi, bi, bh, EWi);
    k_is <<<156,  256, 0, stream>>>(enc, Wenc, EWi, encP, hbuf, cbuf,
                                    actA, encT, nEm, scoresA, packed, sumexp);
    for (int s = 0; s < NS_; ++s){
        int p = s & 1;
        kA<<<128, 256, 0, stream>>>(p, hbuf, encP, Wpred, bj, actA, joint);
        kB<<<128, 256, 0, stream>>>(s, p, joint, Wout, actA, nEm, packed, sumexp);
        kD<<<193, 512, 0, stream>>>(s, p, packed, sumexp, EWi, Whx, hbuf, cbuf,
                                    enc, Wenc, encP, lens, actA, encT, nEm, scoresA, out);
    }
}